// Round 6
// baseline (195.602 us; speedup 1.0000x reference)
//
#include <hip/hip_runtime.h>

#define NN 10000     // nodes
#define HF 128       // hidden feats
#define INF_ 256     // in feats
#define CLS 64       // classes
#define CAP 128      // ushort bucket capacity; deg~Poisson(64), P(max>=128) ~ 2e-7
#define RT  (NN / 16)  // 625 row tiles

typedef __attribute__((ext_vector_type(8))) short short8;   // 8 bf16 (4 VGPRs)
typedef __attribute__((ext_vector_type(4))) float f32x4;

__device__ __forceinline__ unsigned short f2bf(float f) {
    unsigned u = __builtin_bit_cast(unsigned, f);
    u = (u + 0x7fffu + ((u >> 16) & 1u)) >> 16;   // RNE
    return (unsigned short)u;
}
__device__ __forceinline__ float bfbits2f(unsigned u) {  // u = bf16 in low 16
    u <<= 16;
    return __builtin_bit_cast(float, u);
}

// ---------------- MFMA helpers ----------------
// Verified gfx950 fragment layouts (learn_hip m89/m120):
//   A frag: lane holds A[m=lane&15][k=(lane>>4)*8 + 0..7]  (16B contiguous)
//   B frag: lane holds W[n=lane&15][k=(lane>>4)*8 + 0..7]  (W row-major [N][K] = B^T)
//   C/D:    col=lane&15, row=(lane>>4)*4 + reg
// One wave computes a 16x64 output slab (4 accumulators). No LDS, no barriers.

template <int K>
__device__ __forceinline__
void mfma_acc(int row_tile, int col0,
              const unsigned short* __restrict__ A,
              const unsigned short* __restrict__ W, f32x4 acc[4]) {
    int lane = threadIdx.x & 63;
    int m = lane & 15, quad = lane >> 4;
    const short8* ap  = (const short8*)(A + (size_t)(row_tile * 16 + m) * K + quad * 8);
    const short8* bp0 = (const short8*)(W + (size_t)(col0 +  0 + m) * K + quad * 8);
    const short8* bp1 = (const short8*)(W + (size_t)(col0 + 16 + m) * K + quad * 8);
    const short8* bp2 = (const short8*)(W + (size_t)(col0 + 32 + m) * K + quad * 8);
    const short8* bp3 = (const short8*)(W + (size_t)(col0 + 48 + m) * K + quad * 8);
#pragma unroll
    for (int k0 = 0; k0 < K; k0 += 32) {
        int ki = k0 >> 3;
        short8 a = ap[ki];
        acc[0] = __builtin_amdgcn_mfma_f32_16x16x32_bf16(a, bp0[ki], acc[0], 0, 0, 0);
        acc[1] = __builtin_amdgcn_mfma_f32_16x16x32_bf16(a, bp1[ki], acc[1], 0, 0, 0);
        acc[2] = __builtin_amdgcn_mfma_f32_16x16x32_bf16(a, bp2[ki], acc[2], 0, 0, 0);
        acc[3] = __builtin_amdgcn_mfma_f32_16x16x32_bf16(a, bp3[ki], acc[3], 0, 0, 0);
    }
}

// epilogue; optionally adds tmp[row][col] (f32 pre-GEMM partial) before act/store
template <bool OUT_BF16, bool RELU_OUT, bool HAS_BIAS, bool HAS_TMP>
__device__ __forceinline__
void epilogue4(int row_tile, int col0, int N, const float* __restrict__ bias,
               const float* __restrict__ tmp, f32x4 acc[4], void* __restrict__ out) {
    int lane = threadIdx.x & 63;
    int m = lane & 15, quad = lane >> 4;
#pragma unroll
    for (int c = 0; c < 4; ++c) {
        int colg = col0 + c * 16 + m;
        float bv = HAS_BIAS ? bias[colg] : 0.f;
#pragma unroll
        for (int r = 0; r < 4; ++r) {
            int rowg = row_tile * 16 + quad * 4 + r;
            float v = acc[c][r] + bv;
            if (HAS_TMP) v += tmp[(size_t)rowg * N + colg];
            if (RELU_OUT) v = fmaxf(v, 0.f);
            if (OUT_BF16) ((unsigned short*)out)[(size_t)rowg * N + colg] = f2bf(v);
            else          ((float*)out)[(size_t)rowg * N + colg] = v;
        }
    }
}

__device__ __forceinline__ short8 pack8(float4 a, float4 b) {
    short8 r;
    r[0] = (short)f2bf(a.x); r[1] = (short)f2bf(a.y);
    r[2] = (short)f2bf(a.z); r[3] = (short)f2bf(a.w);
    r[4] = (short)f2bf(b.x); r[5] = (short)f2bf(b.y);
    r[6] = (short)f2bf(b.z); r[7] = (short)f2bf(b.w);
    return r;
}

// input projection: h0 = relu(x @ W_lin.T + b_lin); x, W_lin f32 (cvt in-loop —
// hides under the latency-bound fill anyway)
__device__ __forceinline__
void gemm1_wave(int row_tile, int col0, const float* __restrict__ x,
                const float* __restrict__ Wlin, const float* __restrict__ blin,
                unsigned short* __restrict__ h0) {
    int lane = threadIdx.x & 63;
    int m = lane & 15, quad = lane >> 4;
    const float* ar = x    + (size_t)(row_tile * 16 + m) * INF_ + quad * 8;
    const float* w0 = Wlin + (size_t)(col0 +  0 + m) * INF_ + quad * 8;
    const float* w1 = Wlin + (size_t)(col0 + 16 + m) * INF_ + quad * 8;
    const float* w2 = Wlin + (size_t)(col0 + 32 + m) * INF_ + quad * 8;
    const float* w3 = Wlin + (size_t)(col0 + 48 + m) * INF_ + quad * 8;
    f32x4 acc[4] = {};
#pragma unroll
    for (int k0 = 0; k0 < INF_; k0 += 32) {
        short8 a  = pack8(*(const float4*)(ar + k0), *(const float4*)(ar + k0 + 4));
        short8 b0 = pack8(*(const float4*)(w0 + k0), *(const float4*)(w0 + k0 + 4));
        short8 b1 = pack8(*(const float4*)(w1 + k0), *(const float4*)(w1 + k0 + 4));
        short8 b2 = pack8(*(const float4*)(w2 + k0), *(const float4*)(w2 + k0 + 4));
        short8 b3 = pack8(*(const float4*)(w3 + k0), *(const float4*)(w3 + k0 + 4));
        acc[0] = __builtin_amdgcn_mfma_f32_16x16x32_bf16(a, b0, acc[0], 0, 0, 0);
        acc[1] = __builtin_amdgcn_mfma_f32_16x16x32_bf16(a, b1, acc[1], 0, 0, 0);
        acc[2] = __builtin_amdgcn_mfma_f32_16x16x32_bf16(a, b2, acc[2], 0, 0, 0);
        acc[3] = __builtin_amdgcn_mfma_f32_16x16x32_bf16(a, b3, acc[3], 0, 0, 0);
    }
    epilogue4<true, true, true, false>(row_tile, col0, HF, blin, nullptr, acc, h0);
}

// ---------------- fused: gemm1 || bucket fill || weight cvt ----------------
#define GB 313    // gemm1 blocks (2 row-tiles each, covers 625)
#define FB 625    // fill blocks (4 edges/thread: 640000 / (256*4))
#define CB 288    // weight-convert blocks (73728/256)

__global__ __launch_bounds__(256)
void fused_k(const float* __restrict__ x, const float* __restrict__ Wlin,
             const float* __restrict__ blin, unsigned short* __restrict__ h0,
             const int* __restrict__ src, const int* __restrict__ dst,
             int* __restrict__ cnt, unsigned short* __restrict__ colb, int E,
             const float* __restrict__ Wl1, const float* __restrict__ Wr1,
             const float* __restrict__ Wl2, const float* __restrict__ Wr2,
             const float* __restrict__ Wcls, unsigned short* __restrict__ wb) {
    int b = blockIdx.x;
    if (b < GB) {
        int wave = threadIdx.x >> 6;
        int row_tile = b * 2 + (wave >> 1);
        if (row_tile >= RT) return;
        gemm1_wave(row_tile, (wave & 1) * 64, x, Wlin, blin, h0);
    } else if (b < GB + FB) {
        // 4 edges per thread via int4 loads -> 4 independent atomic chains in flight
        int t = (b - GB) * 256 + threadIdx.x;
        if (t * 4 < E) {
            int4 s4 = ((const int4*)src)[t];
            int4 d4 = ((const int4*)dst)[t];
            int p0 = atomicAdd(&cnt[d4.x], 1);
            int p1 = atomicAdd(&cnt[d4.y], 1);
            int p2 = atomicAdd(&cnt[d4.z], 1);
            int p3 = atomicAdd(&cnt[d4.w], 1);
            if (p0 < CAP) colb[(size_t)d4.x * CAP + p0] = (unsigned short)s4.x;
            if (p1 < CAP) colb[(size_t)d4.y * CAP + p1] = (unsigned short)s4.y;
            if (p2 < CAP) colb[(size_t)d4.z * CAP + p2] = (unsigned short)s4.z;
            if (p3 < CAP) colb[(size_t)d4.w * CAP + p3] = (unsigned short)s4.w;
        }
    } else {
        int i = (b - GB - FB) * 256 + threadIdx.x;
        const float* s; int off;
        if      (i < 16384) { s = Wl1;  off = 0; }
        else if (i < 32768) { s = Wr1;  off = 16384; }
        else if (i < 49152) { s = Wl2;  off = 32768; }
        else if (i < 65536) { s = Wr2;  off = 49152; }
        else if (i < 73728) { s = Wcls; off = 65536; }
        else return;
        wb[i] = f2bf(s[i - off]);
    }
}

// ---------------- fused: aggregation || h@Wr GEMM ----------------
// blocks [0, AGB): mean aggregation, one wave per node, quad layout:
//   16 lanes x uint4 (16B) cover a 256B bf16 row; 4 lane-groups process
//   edges j%4==q -> 4 rows in flight per load instruction, 16 steps/chunk.
//   __shfl all-lanes-active (ds_bpermute respects EXEC, R2 bug); break is
//   wave-uniform (mm depends only on node).
// blocks [AGB, AGB+313): tmp = h @ Wr.T (f32) — independent of agg output,
//   hides the half of the SAGE GEMM that doesn't need the mean.
#define AGB 2500

__global__ __launch_bounds__(256)
void agg_gemm_k(const unsigned short* __restrict__ h, const int* __restrict__ cnt,
                const unsigned short* __restrict__ colb, unsigned short* __restrict__ mv,
                const unsigned short* __restrict__ Wr, float* __restrict__ tmp, int n) {
    int b = blockIdx.x;
    if (b < AGB) {
        int wave = threadIdx.x >> 6;
        int lane = threadIdx.x & 63;
        int q   = lane >> 4;       // edge sub-group
        int r16 = lane & 15;       // 16B chunk within row
        int node = b * 4 + wave;
        if (node >= n) return;
        int deg = cnt[node];
        int c = deg > CAP ? CAP : deg;
        const unsigned short* mycol = colb + (size_t)node * CAP;
        const uint4* __restrict__ hp = (const uint4*)h;   // bf16 row = 16 uint4

        float a0 = 0.f, a1 = 0.f, a2 = 0.f, a3 = 0.f;
        float a4 = 0.f, a5 = 0.f, a6 = 0.f, a7 = 0.f;
        for (int base = 0; base < c; base += 64) {
            int mm = min(64, c - base);           // wave-uniform
            int colv = (base + lane < c) ? (int)mycol[base + lane] : 0;
#pragma unroll 4
            for (int jj = 0; jj < 16; ++jj) {
                if (jj * 4 >= mm) break;          // uniform break
                int e = jj * 4 + q;
                int s = __shfl(colv, e);          // all lanes active
                if (e < mm) {
                    uint4 v = hp[(size_t)s * 16 + r16];
                    a0 += bfbits2f(v.x & 0xffffu); a1 += bfbits2f(v.x >> 16);
                    a2 += bfbits2f(v.y & 0xffffu); a3 += bfbits2f(v.y >> 16);
                    a4 += bfbits2f(v.z & 0xffffu); a5 += bfbits2f(v.z >> 16);
                    a6 += bfbits2f(v.w & 0xffffu); a7 += bfbits2f(v.w >> 16);
                }
            }
        }
        // reduce across the 4 lane-groups (bits 4,5) — all lanes active
        a0 += __shfl_xor(a0, 16); a0 += __shfl_xor(a0, 32);
        a1 += __shfl_xor(a1, 16); a1 += __shfl_xor(a1, 32);
        a2 += __shfl_xor(a2, 16); a2 += __shfl_xor(a2, 32);
        a3 += __shfl_xor(a3, 16); a3 += __shfl_xor(a3, 32);
        a4 += __shfl_xor(a4, 16); a4 += __shfl_xor(a4, 32);
        a5 += __shfl_xor(a5, 16); a5 += __shfl_xor(a5, 32);
        a6 += __shfl_xor(a6, 16); a6 += __shfl_xor(a6, 32);
        a7 += __shfl_xor(a7, 16); a7 += __shfl_xor(a7, 32);
        if (q == 0) {
            float inv = (deg > 0) ? 1.0f / (float)deg : 0.f;
            uint4 o;
            o.x = (unsigned)f2bf(a0 * inv) | ((unsigned)f2bf(a1 * inv) << 16);
            o.y = (unsigned)f2bf(a2 * inv) | ((unsigned)f2bf(a3 * inv) << 16);
            o.z = (unsigned)f2bf(a4 * inv) | ((unsigned)f2bf(a5 * inv) << 16);
            o.w = (unsigned)f2bf(a6 * inv) | ((unsigned)f2bf(a7 * inv) << 16);
            ((uint4*)mv)[(size_t)node * 16 + r16] = o;
        }
    } else {
        int bb = b - AGB;
        int wave = threadIdx.x >> 6;
        int row_tile = bb * 2 + (wave >> 1);
        if (row_tile >= RT) return;
        int col0 = (wave & 1) * 64;
        f32x4 acc[4] = {};
        mfma_acc<HF>(row_tile, col0, h, Wr, acc);
        epilogue4<false, false, false, false>(row_tile, col0, HF, nullptr, nullptr, acc, tmp);
    }
}

// ---------------- sage finish: out = mv@Wl.T + tmp + b (bf16 out) ----------------
template <bool RELU_OUT>
__global__ __launch_bounds__(256)
void sage_fin_k(const unsigned short* __restrict__ mv, const unsigned short* __restrict__ Wl,
                const float* __restrict__ tmp, const float* __restrict__ bias,
                unsigned short* __restrict__ out) {
    int wave = threadIdx.x >> 6;
    int row_tile = blockIdx.x * 2 + (wave >> 1);
    if (row_tile >= RT) return;
    int col0 = (wave & 1) * 64;
    f32x4 acc[4] = {};
    mfma_acc<HF>(row_tile, col0, mv, Wl, acc);
    epilogue4<true, RELU_OUT, true, true>(row_tile, col0, HF, bias, tmp, acc, out);
}

// ---------------- classifier: out = h2r @ W_cls.T (f32 out) ----------------
__global__ __launch_bounds__(256)
void cls_gemm_k(const unsigned short* __restrict__ h2r,
                const unsigned short* __restrict__ Wc, float* __restrict__ out) {
    int wave = threadIdx.x >> 6;
    int row_tile = blockIdx.x * 4 + wave;
    if (row_tile >= RT) return;
    f32x4 acc[4] = {};
    mfma_acc<HF>(row_tile, 0, h2r, Wc, acc);
    epilogue4<false, false, false, false>(row_tile, 0, CLS, nullptr, nullptr, acc, out);
}

// ---------------- launch ----------------

extern "C" void kernel_launch(void* const* d_in, const int* in_sizes, int n_in,
                              void* d_out, int out_size, void* d_ws, size_t ws_size,
                              hipStream_t stream) {
    const float* x      = (const float*)d_in[0];
    const int*   ei     = (const int*)d_in[1];
    const float* W_lin  = (const float*)d_in[2];
    const float* b_lin  = (const float*)d_in[3];
    const float* Wl1    = (const float*)d_in[4];
    const float* bl1    = (const float*)d_in[5];
    const float* Wr1    = (const float*)d_in[6];
    const float* Wl2    = (const float*)d_in[7];
    const float* bl2    = (const float*)d_in[8];
    const float* Wr2    = (const float*)d_in[9];
    const float* W_cls  = (const float*)d_in[10];
    float* out = (float*)d_out;

    const int E = in_sizes[1] / 2;
    const int* src = ei;
    const int* dst = ei + E;

    // workspace layout (bf16 stored as ushort)
    unsigned short* wb  = (unsigned short*)d_ws;          // 73728 weights bf16
    unsigned short* wbl1 = wb;
    unsigned short* wbr1 = wb + 16384;
    unsigned short* wbl2 = wb + 32768;
    unsigned short* wbr2 = wb + 49152;
    unsigned short* wbc  = wb + 65536;
    unsigned short* h0  = wb + 73728;                     // NN*HF
    unsigned short* mv  = h0 + (size_t)NN * HF;
    unsigned short* h1  = mv + (size_t)NN * HF;
    unsigned short* h2r = h1 + (size_t)NN * HF;
    float* tmp = (float*)(h2r + (size_t)NN * HF);         // NN*HF f32
    int* cnt = (int*)(tmp + (size_t)NN * HF);             // NN
    unsigned short* colb = (unsigned short*)(cnt + NN);   // NN*CAP

    hipMemsetAsync(cnt, 0, NN * sizeof(int), stream);

    // ---- fused: input projection + relu || bucket fill || weight cvt ----
    fused_k<<<GB + FB + CB, 256, 0, stream>>>(
        x, W_lin, b_lin, h0, src, dst, cnt, colb, E,
        Wl1, Wr1, Wl2, Wr2, W_cls, wb);

    // ---- sage1 ----
    agg_gemm_k<<<AGB + 313, 256, 0, stream>>>(h0, cnt, colb, mv, wbr1, tmp, NN);
    sage_fin_k<false><<<(RT + 1) / 2, 256, 0, stream>>>(mv, wbl1, tmp, bl1, h1);

    // ---- sage2 (fused relu on output) ----
    agg_gemm_k<<<AGB + 313, 256, 0, stream>>>(h1, cnt, colb, mv, wbr2, tmp, NN);
    sage_fin_k<true><<<(RT + 1) / 2, 256, 0, stream>>>(mv, wbl2, tmp, bl2, h2r);

    // ---- classifier ----
    cls_gemm_k<<<(RT + 3) / 4, 256, 0, stream>>>(h2r, wbc, out);
}

// Round 7
// 190.814 us; speedup vs baseline: 1.0251x; 1.0251x over previous
//
#include <hip/hip_runtime.h>

#define NN 10000     // nodes
#define HF 128       // hidden feats
#define INF_ 256     // in feats
#define CLS 64       // classes
#define CAP 128      // ushort bucket capacity; deg~Poisson(64), P(max>=128) ~ 2e-7
#define RT  (NN / 16)  // 625 row tiles

typedef __attribute__((ext_vector_type(8))) short short8;   // 8 bf16 (4 VGPRs)
typedef __attribute__((ext_vector_type(4))) float f32x4;

__device__ __forceinline__ unsigned short f2bf(float f) {
    unsigned u = __builtin_bit_cast(unsigned, f);
    u = (u + 0x7fffu + ((u >> 16) & 1u)) >> 16;   // RNE
    return (unsigned short)u;
}
__device__ __forceinline__ float bfbits2f(unsigned u) {  // u = bf16 in low 16
    u <<= 16;
    return __builtin_bit_cast(float, u);
}

// ---------------- MFMA helpers ----------------
// Verified gfx950 fragment layouts (learn_hip m89/m120):
//   A frag: lane holds A[m=lane&15][k=(lane>>4)*8 + 0..7]  (16B contiguous)
//   B frag: lane holds W[n=lane&15][k=(lane>>4)*8 + 0..7]  (W row-major [N][K] = B^T)
//   C/D:    col=lane&15, row=(lane>>4)*4 + reg
// No LDS, no barriers; NC adjacent 16-col tiles per wave.

template <int K, int NC>
__device__ __forceinline__
void mfma_cols(int row_tile, int col0,
               const unsigned short* __restrict__ A,
               const unsigned short* __restrict__ W, f32x4* acc) {
    int lane = threadIdx.x & 63;
    int m = lane & 15, quad = lane >> 4;
    const short8* ap = (const short8*)(A + (size_t)(row_tile * 16 + m) * K + quad * 8);
    const short8* bp[NC];
#pragma unroll
    for (int c = 0; c < NC; ++c)
        bp[c] = (const short8*)(W + (size_t)(col0 + c * 16 + m) * K + quad * 8);
#pragma unroll
    for (int k0 = 0; k0 < K; k0 += 32) {
        int ki = k0 >> 3;
        short8 a = ap[ki];
#pragma unroll
        for (int c = 0; c < NC; ++c)
            acc[c] = __builtin_amdgcn_mfma_f32_16x16x32_bf16(a, bp[c][ki], acc[c], 0, 0, 0);
    }
}

// epilogue; optionally adds tmp[row][col] (f32 partial) before act/store
template <int NC, bool OUT_BF16, bool RELU_OUT, bool HAS_BIAS, bool HAS_TMP>
__device__ __forceinline__
void epilogue_n(int row_tile, int col0, int N, const float* __restrict__ bias,
                const float* __restrict__ tmp, f32x4* acc, void* __restrict__ out) {
    int lane = threadIdx.x & 63;
    int m = lane & 15, quad = lane >> 4;
#pragma unroll
    for (int c = 0; c < NC; ++c) {
        int colg = col0 + c * 16 + m;
        float bv = HAS_BIAS ? bias[colg] : 0.f;
#pragma unroll
        for (int r = 0; r < 4; ++r) {
            int rowg = row_tile * 16 + quad * 4 + r;
            float v = acc[c][r] + bv;
            if (HAS_TMP) v += tmp[(size_t)rowg * N + colg];
            if (RELU_OUT) v = fmaxf(v, 0.f);
            if (OUT_BF16) ((unsigned short*)out)[(size_t)rowg * N + colg] = f2bf(v);
            else          ((float*)out)[(size_t)rowg * N + colg] = v;
        }
    }
}

__device__ __forceinline__ short8 pack8(float4 a, float4 b) {
    short8 r;
    r[0] = (short)f2bf(a.x); r[1] = (short)f2bf(a.y);
    r[2] = (short)f2bf(a.z); r[3] = (short)f2bf(a.w);
    r[4] = (short)f2bf(b.x); r[5] = (short)f2bf(b.y);
    r[6] = (short)f2bf(b.z); r[7] = (short)f2bf(b.w);
    return r;
}

// input projection: h0 = relu(x @ W_lin.T + b_lin); x, W_lin f32 (cvt in-loop —
// hides under the latency-bound fill anyway)
__device__ __forceinline__
void gemm1_wave(int row_tile, int col0, const float* __restrict__ x,
                const float* __restrict__ Wlin, const float* __restrict__ blin,
                unsigned short* __restrict__ h0) {
    int lane = threadIdx.x & 63;
    int m = lane & 15, quad = lane >> 4;
    const float* ar = x    + (size_t)(row_tile * 16 + m) * INF_ + quad * 8;
    const float* w0 = Wlin + (size_t)(col0 +  0 + m) * INF_ + quad * 8;
    const float* w1 = Wlin + (size_t)(col0 + 16 + m) * INF_ + quad * 8;
    const float* w2 = Wlin + (size_t)(col0 + 32 + m) * INF_ + quad * 8;
    const float* w3 = Wlin + (size_t)(col0 + 48 + m) * INF_ + quad * 8;
    f32x4 acc[4] = {};
#pragma unroll
    for (int k0 = 0; k0 < INF_; k0 += 32) {
        short8 a  = pack8(*(const float4*)(ar + k0), *(const float4*)(ar + k0 + 4));
        short8 b0 = pack8(*(const float4*)(w0 + k0), *(const float4*)(w0 + k0 + 4));
        short8 b1 = pack8(*(const float4*)(w1 + k0), *(const float4*)(w1 + k0 + 4));
        short8 b2 = pack8(*(const float4*)(w2 + k0), *(const float4*)(w2 + k0 + 4));
        short8 b3 = pack8(*(const float4*)(w3 + k0), *(const float4*)(w3 + k0 + 4));
        acc[0] = __builtin_amdgcn_mfma_f32_16x16x32_bf16(a, b0, acc[0], 0, 0, 0);
        acc[1] = __builtin_amdgcn_mfma_f32_16x16x32_bf16(a, b1, acc[1], 0, 0, 0);
        acc[2] = __builtin_amdgcn_mfma_f32_16x16x32_bf16(a, b2, acc[2], 0, 0, 0);
        acc[3] = __builtin_amdgcn_mfma_f32_16x16x32_bf16(a, b3, acc[3], 0, 0, 0);
    }
    epilogue_n<4, true, true, true, false>(row_tile, col0, HF, blin, nullptr, acc, h0);
}

// ---------------- fused: gemm1 || bucket fill || weight cvt ----------------
#define GB 313    // gemm1 blocks (2 row-tiles each, covers 625)
#define FB 2500   // fill blocks: 1 edge/thread (R6 lesson: waves > per-thread ILP)
#define CB 288    // weight-convert blocks (73728/256)

__global__ __launch_bounds__(256)
void fused_k(const float* __restrict__ x, const float* __restrict__ Wlin,
             const float* __restrict__ blin, unsigned short* __restrict__ h0,
             const int* __restrict__ src, const int* __restrict__ dst,
             int* __restrict__ cnt, unsigned short* __restrict__ colb, int E,
             const float* __restrict__ Wl1, const float* __restrict__ Wr1,
             const float* __restrict__ Wl2, const float* __restrict__ Wr2,
             const float* __restrict__ Wcls, unsigned short* __restrict__ wb) {
    int b = blockIdx.x;
    if (b < GB) {
        int wave = threadIdx.x >> 6;
        int row_tile = b * 2 + (wave >> 1);
        if (row_tile >= RT) return;
        gemm1_wave(row_tile, (wave & 1) * 64, x, Wlin, blin, h0);
    } else if (b < GB + FB) {
        int i = (b - GB) * 256 + threadIdx.x;
        if (i < E) {
            int d = dst[i];
            int pos = atomicAdd(&cnt[d], 1);
            if (pos < CAP) colb[(size_t)d * CAP + pos] = (unsigned short)src[i];
        }
    } else {
        int i = (b - GB - FB) * 256 + threadIdx.x;
        const float* s; int off;
        if      (i < 16384) { s = Wl1;  off = 0; }
        else if (i < 32768) { s = Wr1;  off = 16384; }
        else if (i < 49152) { s = Wl2;  off = 32768; }
        else if (i < 65536) { s = Wr2;  off = 49152; }
        else if (i < 73728) { s = Wcls; off = 65536; }
        else return;
        wb[i] = f2bf(s[i - off]);
    }
}

// ---------------- fused: aggregation || h@Wr GEMM ----------------
// blocks [0, AGB): mean aggregation, TWO waves per node (wave w handles edge
//   chunk [64w, 64w+64) of the CAP=128 bucket), partials merged via LDS —
//   doubles the wave pool hiding the shfl->gather latency chain.
//   Quad layout: 16 lanes x uint4 cover a 256B bf16 row; 4 lane-groups = 4
//   edges in flight per load inst. __shfl all-lanes-active (R2 bug).
// blocks [AGB, AGB+RT): tmp = h @ Wr.T (f32), one row-tile/block, 4 waves x 32 cols.
#define AGB 5000

__global__ __launch_bounds__(256)
void agg_gemm_k(const unsigned short* __restrict__ h, const int* __restrict__ cnt,
                const unsigned short* __restrict__ colb, unsigned short* __restrict__ mv,
                const unsigned short* __restrict__ Wr, float* __restrict__ tmp, int n) {
    int b = blockIdx.x;
    if (b < AGB) {
        __shared__ float part[4][8][16];   // [wave][elem][r16]
        int wave = threadIdx.x >> 6;
        int lane = threadIdx.x & 63;
        int w    = wave & 1;               // edge-chunk half
        int q    = lane >> 4;              // edge sub-group
        int r16  = lane & 15;              // 16B chunk within row
        int node = b * 2 + (wave >> 1);
        int deg = cnt[node];
        int c = deg > CAP ? CAP : deg;
        // this wave's chunk: [w*64, min(c, w*64+64))
        int cw = c - w * 64;
        cw = cw < 0 ? 0 : (cw > 64 ? 64 : cw);
        const unsigned short* mycol = colb + (size_t)node * CAP + w * 64;
        const uint4* __restrict__ hp = (const uint4*)h;   // bf16 row = 16 uint4

        float a0 = 0.f, a1 = 0.f, a2 = 0.f, a3 = 0.f;
        float a4 = 0.f, a5 = 0.f, a6 = 0.f, a7 = 0.f;
        int colv = (lane < cw) ? (int)mycol[lane] : 0;
#pragma unroll 4
        for (int jj = 0; jj < 16; ++jj) {
            if (jj * 4 >= cw) break;          // wave-uniform break
            int e = jj * 4 + q;
            int s = __shfl(colv, e);          // all lanes active
            if (e < cw) {
                uint4 v = hp[(size_t)s * 16 + r16];
                a0 += bfbits2f(v.x & 0xffffu); a1 += bfbits2f(v.x >> 16);
                a2 += bfbits2f(v.y & 0xffffu); a3 += bfbits2f(v.y >> 16);
                a4 += bfbits2f(v.z & 0xffffu); a5 += bfbits2f(v.z >> 16);
                a6 += bfbits2f(v.w & 0xffffu); a7 += bfbits2f(v.w >> 16);
            }
        }
        // reduce across the 4 lane-groups (bits 4,5) — all lanes active
        a0 += __shfl_xor(a0, 16); a0 += __shfl_xor(a0, 32);
        a1 += __shfl_xor(a1, 16); a1 += __shfl_xor(a1, 32);
        a2 += __shfl_xor(a2, 16); a2 += __shfl_xor(a2, 32);
        a3 += __shfl_xor(a3, 16); a3 += __shfl_xor(a3, 32);
        a4 += __shfl_xor(a4, 16); a4 += __shfl_xor(a4, 32);
        a5 += __shfl_xor(a5, 16); a5 += __shfl_xor(a5, 32);
        a6 += __shfl_xor(a6, 16); a6 += __shfl_xor(a6, 32);
        a7 += __shfl_xor(a7, 16); a7 += __shfl_xor(a7, 32);
        if (q == 0) {
            part[wave][0][r16] = a0; part[wave][1][r16] = a1;
            part[wave][2][r16] = a2; part[wave][3][r16] = a3;
            part[wave][4][r16] = a4; part[wave][5][r16] = a5;
            part[wave][6][r16] = a6; part[wave][7][r16] = a7;
        }
        __syncthreads();
        if (w == 0 && q == 0) {
            float inv = (deg > 0) ? 1.0f / (float)deg : 0.f;
            float s0 = (part[wave][0][r16] + part[wave + 1][0][r16]) * inv;
            float s1 = (part[wave][1][r16] + part[wave + 1][1][r16]) * inv;
            float s2 = (part[wave][2][r16] + part[wave + 1][2][r16]) * inv;
            float s3 = (part[wave][3][r16] + part[wave + 1][3][r16]) * inv;
            float s4 = (part[wave][4][r16] + part[wave + 1][4][r16]) * inv;
            float s5 = (part[wave][5][r16] + part[wave + 1][5][r16]) * inv;
            float s6 = (part[wave][6][r16] + part[wave + 1][6][r16]) * inv;
            float s7 = (part[wave][7][r16] + part[wave + 1][7][r16]) * inv;
            uint4 o;
            o.x = (unsigned)f2bf(s0) | ((unsigned)f2bf(s1) << 16);
            o.y = (unsigned)f2bf(s2) | ((unsigned)f2bf(s3) << 16);
            o.z = (unsigned)f2bf(s4) | ((unsigned)f2bf(s5) << 16);
            o.w = (unsigned)f2bf(s6) | ((unsigned)f2bf(s7) << 16);
            ((uint4*)mv)[(size_t)node * 16 + r16] = o;
        }
    } else {
        // tmp = h @ Wr.T : one row-tile per block, 4 waves x 32 cols
        int row_tile = b - AGB;
        int wave = threadIdx.x >> 6;
        f32x4 acc[2] = {};
        mfma_cols<HF, 2>(row_tile, wave * 32, h, Wr, acc);
        epilogue_n<2, false, false, false, false>(row_tile, wave * 32, HF,
                                                  nullptr, nullptr, acc, tmp);
    }
}

// ---------------- sage finish: out = mv@Wl.T + tmp + b (bf16 out) ----------------
// one row-tile per block, 4 waves x 32 cols (625 blocks, ~2.4/CU)
template <bool RELU_OUT>
__global__ __launch_bounds__(256)
void sage_fin_k(const unsigned short* __restrict__ mv, const unsigned short* __restrict__ Wl,
                const float* __restrict__ tmp, const float* __restrict__ bias,
                unsigned short* __restrict__ out) {
    int row_tile = blockIdx.x;
    int wave = threadIdx.x >> 6;
    f32x4 acc[2] = {};
    mfma_cols<HF, 2>(row_tile, wave * 32, mv, Wl, acc);
    epilogue_n<2, true, RELU_OUT, true, true>(row_tile, wave * 32, HF,
                                              bias, tmp, acc, out);
}

// ---------------- classifier: out = h2r @ W_cls.T (f32 out) ----------------
// one row-tile per block, 4 waves x 16 cols (625 blocks)
__global__ __launch_bounds__(256)
void cls_gemm_k(const unsigned short* __restrict__ h2r,
                const unsigned short* __restrict__ Wc, float* __restrict__ out) {
    int row_tile = blockIdx.x;
    int wave = threadIdx.x >> 6;
    f32x4 acc[1] = {};
    mfma_cols<HF, 1>(row_tile, wave * 16, h2r, Wc, acc);
    epilogue_n<1, false, false, false, false>(row_tile, wave * 16, CLS,
                                              nullptr, nullptr, acc, out);
}

// ---------------- launch ----------------

extern "C" void kernel_launch(void* const* d_in, const int* in_sizes, int n_in,
                              void* d_out, int out_size, void* d_ws, size_t ws_size,
                              hipStream_t stream) {
    const float* x      = (const float*)d_in[0];
    const int*   ei     = (const int*)d_in[1];
    const float* W_lin  = (const float*)d_in[2];
    const float* b_lin  = (const float*)d_in[3];
    const float* Wl1    = (const float*)d_in[4];
    const float* bl1    = (const float*)d_in[5];
    const float* Wr1    = (const float*)d_in[6];
    const float* Wl2    = (const float*)d_in[7];
    const float* bl2    = (const float*)d_in[8];
    const float* Wr2    = (const float*)d_in[9];
    const float* W_cls  = (const float*)d_in[10];
    float* out = (float*)d_out;

    const int E = in_sizes[1] / 2;
    const int* src = ei;
    const int* dst = ei + E;

    // workspace layout (bf16 stored as ushort)
    unsigned short* wb  = (unsigned short*)d_ws;          // 73728 weights bf16
    unsigned short* wbl1 = wb;
    unsigned short* wbr1 = wb + 16384;
    unsigned short* wbl2 = wb + 32768;
    unsigned short* wbr2 = wb + 49152;
    unsigned short* wbc  = wb + 65536;
    unsigned short* h0  = wb + 73728;                     // NN*HF
    unsigned short* mv  = h0 + (size_t)NN * HF;
    unsigned short* h1  = mv + (size_t)NN * HF;
    unsigned short* h2r = h1 + (size_t)NN * HF;
    float* tmp = (float*)(h2r + (size_t)NN * HF);         // NN*HF f32
    int* cnt = (int*)(tmp + (size_t)NN * HF);             // NN
    unsigned short* colb = (unsigned short*)(cnt + NN);   // NN*CAP

    hipMemsetAsync(cnt, 0, NN * sizeof(int), stream);

    // ---- fused: input projection + relu || bucket fill || weight cvt ----
    fused_k<<<GB + FB + CB, 256, 0, stream>>>(
        x, W_lin, b_lin, h0, src, dst, cnt, colb, E,
        Wl1, Wr1, Wl2, Wr2, W_cls, wb);

    // ---- sage1 ----
    agg_gemm_k<<<AGB + RT, 256, 0, stream>>>(h0, cnt, colb, mv, wbr1, tmp, NN);
    sage_fin_k<false><<<RT, 256, 0, stream>>>(mv, wbl1, tmp, bl1, h1);

    // ---- sage2 (fused relu on output) ----
    agg_gemm_k<<<AGB + RT, 256, 0, stream>>>(h1, cnt, colb, mv, wbr2, tmp, NN);
    sage_fin_k<true><<<RT, 256, 0, stream>>>(mv, wbl2, tmp, bl2, h2r);

    // ---- classifier ----
    cls_gemm_k<<<RT, 256, 0, stream>>>(h2r, wbc, out);
}

// Round 8
// 181.365 us; speedup vs baseline: 1.0785x; 1.0521x over previous
//
#include <hip/hip_runtime.h>

#define NN 10000     // nodes
#define HF 128       // hidden feats
#define INF_ 256     // in feats
#define CLS 64       // classes
#define CAP 128      // ushort bucket capacity; deg~Poisson(64), P(max>=128) ~ 2e-7
#define RT  (NN / 16)  // 625 row tiles

typedef __attribute__((ext_vector_type(8))) short short8;   // 8 bf16 (4 VGPRs)
typedef __attribute__((ext_vector_type(4))) float f32x4;

__device__ __forceinline__ unsigned short f2bf(float f) {
    unsigned u = __builtin_bit_cast(unsigned, f);
    u = (u + 0x7fffu + ((u >> 16) & 1u)) >> 16;   // RNE
    return (unsigned short)u;
}
__device__ __forceinline__ float bfbits2f(unsigned u) {  // u = bf16 in low 16
    u <<= 16;
    return __builtin_bit_cast(float, u);
}

// ---------------- MFMA helpers ----------------
// Verified gfx950 fragment layouts (learn_hip m89/m120):
//   A frag: lane holds A[m=lane&15][k=(lane>>4)*8 + 0..7]  (16B contiguous)
//   B frag: lane holds W[n=lane&15][k=(lane>>4)*8 + 0..7]  (W row-major [N][K] = B^T)
//   C/D:    col=lane&15, row=(lane>>4)*4 + reg
// No LDS, no barriers; NC adjacent 16-col tiles per wave.

template <int K, int NC>
__device__ __forceinline__
void mfma_cols(int row_tile, int col0,
               const unsigned short* __restrict__ A,
               const unsigned short* __restrict__ W, f32x4* acc) {
    int lane = threadIdx.x & 63;
    int m = lane & 15, quad = lane >> 4;
    const short8* ap = (const short8*)(A + (size_t)(row_tile * 16 + m) * K + quad * 8);
    const short8* bp[NC];
#pragma unroll
    for (int c = 0; c < NC; ++c)
        bp[c] = (const short8*)(W + (size_t)(col0 + c * 16 + m) * K + quad * 8);
#pragma unroll
    for (int k0 = 0; k0 < K; k0 += 32) {
        int ki = k0 >> 3;
        short8 a = ap[ki];
#pragma unroll
        for (int c = 0; c < NC; ++c)
            acc[c] = __builtin_amdgcn_mfma_f32_16x16x32_bf16(a, bp[c][ki], acc[c], 0, 0, 0);
    }
}

// epilogue; optionally adds tmp[row][col] (f32 partial) before act/store
template <int NC, bool OUT_BF16, bool RELU_OUT, bool HAS_BIAS, bool HAS_TMP>
__device__ __forceinline__
void epilogue_n(int row_tile, int col0, int N, const float* __restrict__ bias,
                const float* __restrict__ tmp, f32x4* acc, void* __restrict__ out) {
    int lane = threadIdx.x & 63;
    int m = lane & 15, quad = lane >> 4;
#pragma unroll
    for (int c = 0; c < NC; ++c) {
        int colg = col0 + c * 16 + m;
        float bv = HAS_BIAS ? bias[colg] : 0.f;
#pragma unroll
        for (int r = 0; r < 4; ++r) {
            int rowg = row_tile * 16 + quad * 4 + r;
            float v = acc[c][r] + bv;
            if (HAS_TMP) v += tmp[(size_t)rowg * N + colg];
            if (RELU_OUT) v = fmaxf(v, 0.f);
            if (OUT_BF16) ((unsigned short*)out)[(size_t)rowg * N + colg] = f2bf(v);
            else          ((float*)out)[(size_t)rowg * N + colg] = v;
        }
    }
}

__device__ __forceinline__ short8 pack8(float4 a, float4 b) {
    short8 r;
    r[0] = (short)f2bf(a.x); r[1] = (short)f2bf(a.y);
    r[2] = (short)f2bf(a.z); r[3] = (short)f2bf(a.w);
    r[4] = (short)f2bf(b.x); r[5] = (short)f2bf(b.y);
    r[6] = (short)f2bf(b.z); r[7] = (short)f2bf(b.w);
    return r;
}

// input projection: h0 = relu(x @ W_lin.T + b_lin); x, W_lin f32 (cvt in-loop —
// hides under the latency-bound fill anyway)
__device__ __forceinline__
void gemm1_wave(int row_tile, int col0, const float* __restrict__ x,
                const float* __restrict__ Wlin, const float* __restrict__ blin,
                unsigned short* __restrict__ h0) {
    int lane = threadIdx.x & 63;
    int m = lane & 15, quad = lane >> 4;
    const float* ar = x    + (size_t)(row_tile * 16 + m) * INF_ + quad * 8;
    const float* w0 = Wlin + (size_t)(col0 +  0 + m) * INF_ + quad * 8;
    const float* w1 = Wlin + (size_t)(col0 + 16 + m) * INF_ + quad * 8;
    const float* w2 = Wlin + (size_t)(col0 + 32 + m) * INF_ + quad * 8;
    const float* w3 = Wlin + (size_t)(col0 + 48 + m) * INF_ + quad * 8;
    f32x4 acc[4] = {};
#pragma unroll
    for (int k0 = 0; k0 < INF_; k0 += 32) {
        short8 a  = pack8(*(const float4*)(ar + k0), *(const float4*)(ar + k0 + 4));
        short8 b0 = pack8(*(const float4*)(w0 + k0), *(const float4*)(w0 + k0 + 4));
        short8 b1 = pack8(*(const float4*)(w1 + k0), *(const float4*)(w1 + k0 + 4));
        short8 b2 = pack8(*(const float4*)(w2 + k0), *(const float4*)(w2 + k0 + 4));
        short8 b3 = pack8(*(const float4*)(w3 + k0), *(const float4*)(w3 + k0 + 4));
        acc[0] = __builtin_amdgcn_mfma_f32_16x16x32_bf16(a, b0, acc[0], 0, 0, 0);
        acc[1] = __builtin_amdgcn_mfma_f32_16x16x32_bf16(a, b1, acc[1], 0, 0, 0);
        acc[2] = __builtin_amdgcn_mfma_f32_16x16x32_bf16(a, b2, acc[2], 0, 0, 0);
        acc[3] = __builtin_amdgcn_mfma_f32_16x16x32_bf16(a, b3, acc[3], 0, 0, 0);
    }
    epilogue_n<4, true, true, true, false>(row_tile, col0, HF, blin, nullptr, acc, h0);
}

// ---------------- fused: gemm1 || bucket fill || weight cvt ----------------
#define GB 313    // gemm1 blocks (2 row-tiles each, covers 625)
#define FB 2500   // fill blocks: 1 edge/thread (R6 lesson: waves > per-thread ILP)
#define CB 288    // weight-convert blocks (73728/256)

__global__ __launch_bounds__(256)
void fused_k(const float* __restrict__ x, const float* __restrict__ Wlin,
             const float* __restrict__ blin, unsigned short* __restrict__ h0,
             const int* __restrict__ src, const int* __restrict__ dst,
             int* __restrict__ cnt, unsigned short* __restrict__ colb, int E,
             const float* __restrict__ Wl1, const float* __restrict__ Wr1,
             const float* __restrict__ Wl2, const float* __restrict__ Wr2,
             const float* __restrict__ Wcls, unsigned short* __restrict__ wb) {
    int b = blockIdx.x;
    if (b < GB) {
        int wave = threadIdx.x >> 6;
        int row_tile = b * 2 + (wave >> 1);
        if (row_tile >= RT) return;
        gemm1_wave(row_tile, (wave & 1) * 64, x, Wlin, blin, h0);
    } else if (b < GB + FB) {
        int i = (b - GB) * 256 + threadIdx.x;
        if (i < E) {
            int d = dst[i];
            int pos = atomicAdd(&cnt[d], 1);
            if (pos < CAP) colb[(size_t)d * CAP + pos] = (unsigned short)src[i];
        }
    } else {
        int i = (b - GB - FB) * 256 + threadIdx.x;
        const float* s; int off;
        if      (i < 16384) { s = Wl1;  off = 0; }
        else if (i < 32768) { s = Wr1;  off = 16384; }
        else if (i < 49152) { s = Wl2;  off = 32768; }
        else if (i < 65536) { s = Wr2;  off = 49152; }
        else if (i < 73728) { s = Wcls; off = 65536; }
        else return;
        wb[i] = f2bf(s[i - off]);
    }
}

// ---------------- fused: aggregation || h@Wr GEMM (R6 structure) ----------------
// blocks [0, AGB): mean aggregation, ONE wave per node, quad layout:
//   16 lanes x uint4 (16B) cover a 256B bf16 row; 4 lane-groups process
//   edges j%4==q -> 4 rows in flight per load instruction.
//   __shfl all-lanes-active (ds_bpermute respects EXEC, R2 bug); break is
//   wave-uniform (mm depends only on node).
// blocks [AGB, AGB+313): tmp = h @ Wr.T (f32), 2 row-tiles/block, 64 cols/wave.
#define AGB 2500

__global__ __launch_bounds__(256)
void agg_gemm_k(const unsigned short* __restrict__ h, const int* __restrict__ cnt,
                const unsigned short* __restrict__ colb, unsigned short* __restrict__ mv,
                const unsigned short* __restrict__ Wr, float* __restrict__ tmp, int n) {
    int b = blockIdx.x;
    if (b < AGB) {
        int wave = threadIdx.x >> 6;
        int lane = threadIdx.x & 63;
        int q   = lane >> 4;       // edge sub-group
        int r16 = lane & 15;       // 16B chunk within row
        int node = b * 4 + wave;
        if (node >= n) return;
        int deg = cnt[node];
        int c = deg > CAP ? CAP : deg;
        const unsigned short* mycol = colb + (size_t)node * CAP;
        const uint4* __restrict__ hp = (const uint4*)h;   // bf16 row = 16 uint4

        float a0 = 0.f, a1 = 0.f, a2 = 0.f, a3 = 0.f;
        float a4 = 0.f, a5 = 0.f, a6 = 0.f, a7 = 0.f;
        for (int base = 0; base < c; base += 64) {
            int mm = min(64, c - base);           // wave-uniform
            int colv = (base + lane < c) ? (int)mycol[base + lane] : 0;
#pragma unroll 4
            for (int jj = 0; jj < 16; ++jj) {
                if (jj * 4 >= mm) break;          // uniform break
                int e = jj * 4 + q;
                int s = __shfl(colv, e);          // all lanes active
                if (e < mm) {
                    uint4 v = hp[(size_t)s * 16 + r16];
                    a0 += bfbits2f(v.x & 0xffffu); a1 += bfbits2f(v.x >> 16);
                    a2 += bfbits2f(v.y & 0xffffu); a3 += bfbits2f(v.y >> 16);
                    a4 += bfbits2f(v.z & 0xffffu); a5 += bfbits2f(v.z >> 16);
                    a6 += bfbits2f(v.w & 0xffffu); a7 += bfbits2f(v.w >> 16);
                }
            }
        }
        // reduce across the 4 lane-groups (bits 4,5) — all lanes active
        a0 += __shfl_xor(a0, 16); a0 += __shfl_xor(a0, 32);
        a1 += __shfl_xor(a1, 16); a1 += __shfl_xor(a1, 32);
        a2 += __shfl_xor(a2, 16); a2 += __shfl_xor(a2, 32);
        a3 += __shfl_xor(a3, 16); a3 += __shfl_xor(a3, 32);
        a4 += __shfl_xor(a4, 16); a4 += __shfl_xor(a4, 32);
        a5 += __shfl_xor(a5, 16); a5 += __shfl_xor(a5, 32);
        a6 += __shfl_xor(a6, 16); a6 += __shfl_xor(a6, 32);
        a7 += __shfl_xor(a7, 16); a7 += __shfl_xor(a7, 32);
        if (q == 0) {
            float inv = (deg > 0) ? 1.0f / (float)deg : 0.f;
            uint4 o;
            o.x = (unsigned)f2bf(a0 * inv) | ((unsigned)f2bf(a1 * inv) << 16);
            o.y = (unsigned)f2bf(a2 * inv) | ((unsigned)f2bf(a3 * inv) << 16);
            o.z = (unsigned)f2bf(a4 * inv) | ((unsigned)f2bf(a5 * inv) << 16);
            o.w = (unsigned)f2bf(a6 * inv) | ((unsigned)f2bf(a7 * inv) << 16);
            ((uint4*)mv)[(size_t)node * 16 + r16] = o;
        }
    } else {
        // tmp = h @ Wr.T : 2 row-tiles per block, 64 cols (NC=4) per wave
        int bb = b - AGB;
        int wave = threadIdx.x >> 6;
        int row_tile = bb * 2 + (wave >> 1);
        if (row_tile >= RT) return;
        int col0 = (wave & 1) * 64;
        f32x4 acc[4] = {};
        mfma_cols<HF, 4>(row_tile, col0, h, Wr, acc);
        epilogue_n<4, false, false, false, false>(row_tile, col0, HF,
                                                  nullptr, nullptr, acc, tmp);
    }
}

// ---------------- sage1 finish: h1 = mv@Wl.T + tmp + b (bf16 out) ----------------
// 2 row-tiles per block, 64 cols (NC=4) per wave (313 blocks) — R6 structure
__global__ __launch_bounds__(256)
void sage_fin_k(const unsigned short* __restrict__ mv, const unsigned short* __restrict__ Wl,
                const float* __restrict__ tmp, const float* __restrict__ bias,
                unsigned short* __restrict__ out) {
    int wave = threadIdx.x >> 6;
    int row_tile = blockIdx.x * 2 + (wave >> 1);
    if (row_tile >= RT) return;
    int col0 = (wave & 1) * 64;
    f32x4 acc[4] = {};
    mfma_cols<HF, 4>(row_tile, col0, mv, Wl, acc);
    epilogue_n<4, true, false, true, true>(row_tile, col0, HF, bias, tmp, acc, out);
}

// ---------------- sage2 finish + classifier (fused, h2 never hits global) ----
// Per block: 2 row-tiles. Phase 1: h2 = relu(mv@Wl2.T + tmp + b) -> LDS (bf16).
// Phase 2 (after barrier): out = h2_lds @ W_cls.T (K=128 from LDS, f32 out).
// Block 312 covers tile 625 (doesn't exist): row_tile CLAMPED to 624 ->
// redundant identical work/stores (benign) — early return would deadlock the
// barrier.
__global__ __launch_bounds__(256)
void fin2_cls_k(const unsigned short* __restrict__ mv, const unsigned short* __restrict__ Wl,
                const float* __restrict__ tmp, const float* __restrict__ bias,
                const unsigned short* __restrict__ Wc, float* __restrict__ out) {
    __shared__ unsigned short h2s[2][16][HF];   // 8 KB
    int wave = threadIdx.x >> 6;
    int lane = threadIdx.x & 63;
    int m = lane & 15, quad = lane >> 4;

    // ---- phase 1: h2 row-tile -> LDS ----
    int t1 = wave >> 1;
    int rt1 = blockIdx.x * 2 + t1;
    if (rt1 >= RT) rt1 = RT - 1;            // clamp, keep all waves alive
    int col0 = (wave & 1) * 64;
    f32x4 acc[4] = {};
    mfma_cols<HF, 4>(rt1, col0, mv, Wl, acc);
#pragma unroll
    for (int c = 0; c < 4; ++c) {
        int colg = col0 + c * 16 + m;
        float bv = bias[colg];
#pragma unroll
        for (int r = 0; r < 4; ++r) {
            int rl = quad * 4 + r;
            float v = acc[c][r] + bv + tmp[(size_t)(rt1 * 16 + rl) * HF + colg];
            h2s[t1][rl][colg] = f2bf(fmaxf(v, 0.f));
        }
    }
    __syncthreads();

    // ---- phase 2: cls from LDS. wave handles tile (wave>>1), 32 cols ----
    int t2 = wave >> 1;
    int rt2 = blockIdx.x * 2 + t2;
    if (rt2 >= RT) rt2 = RT - 1;            // duplicate of tile 624 data (identical)
    int cc0 = (wave & 1) * 32;
    const unsigned short* As = &h2s[t2][0][0];   // row stride = HF
    f32x4 cacc[2] = {};
    mfma_cols<HF, 2>(0, cc0, As, Wc, cacc);
    epilogue_n<2, false, false, false, false>(0, 0, 0, nullptr, nullptr, cacc, nullptr);
    // manual store with global row base (epilogue_n's row_tile math doesn't fit here)
#pragma unroll
    for (int c = 0; c < 2; ++c) {
        int colg = cc0 + c * 16 + m;
#pragma unroll
        for (int r = 0; r < 4; ++r) {
            int rowg = rt2 * 16 + quad * 4 + r;
            out[(size_t)rowg * CLS + colg] = cacc[c][r];
        }
    }
}

// ---------------- launch ----------------

extern "C" void kernel_launch(void* const* d_in, const int* in_sizes, int n_in,
                              void* d_out, int out_size, void* d_ws, size_t ws_size,
                              hipStream_t stream) {
    const float* x      = (const float*)d_in[0];
    const int*   ei     = (const int*)d_in[1];
    const float* W_lin  = (const float*)d_in[2];
    const float* b_lin  = (const float*)d_in[3];
    const float* Wl1    = (const float*)d_in[4];
    const float* bl1    = (const float*)d_in[5];
    const float* Wr1    = (const float*)d_in[6];
    const float* Wl2    = (const float*)d_in[7];
    const float* bl2    = (const float*)d_in[8];
    const float* Wr2    = (const float*)d_in[9];
    const float* W_cls  = (const float*)d_in[10];
    float* out = (float*)d_out;

    const int E = in_sizes[1] / 2;
    const int* src = ei;
    const int* dst = ei + E;

    // workspace layout (bf16 stored as ushort)
    unsigned short* wb  = (unsigned short*)d_ws;          // 73728 weights bf16
    unsigned short* wbl1 = wb;
    unsigned short* wbr1 = wb + 16384;
    unsigned short* wbl2 = wb + 32768;
    unsigned short* wbr2 = wb + 49152;
    unsigned short* wbc  = wb + 65536;
    unsigned short* h0  = wb + 73728;                     // NN*HF
    unsigned short* mv  = h0 + (size_t)NN * HF;
    unsigned short* h1  = mv + (size_t)NN * HF;
    float* tmp = (float*)(h1 + (size_t)NN * HF);          // NN*HF f32
    int* cnt = (int*)(tmp + (size_t)NN * HF);             // NN
    unsigned short* colb = (unsigned short*)(cnt + NN);   // NN*CAP

    hipMemsetAsync(cnt, 0, NN * sizeof(int), stream);

    // ---- fused: input projection + relu || bucket fill || weight cvt ----
    fused_k<<<GB + FB + CB, 256, 0, stream>>>(
        x, W_lin, b_lin, h0, src, dst, cnt, colb, E,
        Wl1, Wr1, Wl2, Wr2, W_cls, wb);

    // ---- sage1 ----
    agg_gemm_k<<<AGB + 313, 256, 0, stream>>>(h0, cnt, colb, mv, wbr1, tmp, NN);
    sage_fin_k<<<313, 256, 0, stream>>>(mv, wbl1, tmp, bl1, h1);

    // ---- sage2 + classifier (fused) ----
    agg_gemm_k<<<AGB + 313, 256, 0, stream>>>(h1, cnt, colb, mv, wbr2, tmp, NN);
    fin2_cls_k<<<313, 256, 0, stream>>>(mv, wbl2, tmp, bl2, wbc, out);
}

// Round 9
// 170.046 us; speedup vs baseline: 1.1503x; 1.0666x over previous
//
#include <hip/hip_runtime.h>

#define NN 10000     // nodes
#define HF 128       // hidden feats
#define INF_ 256     // in feats
#define CLS 64       // classes
#define CAP 128      // ushort bucket capacity; deg~Poisson(64), P(max>=128) ~ 2e-7
#define RT  (NN / 16)  // 625 row tiles
#define LDP (HF + 8)   // padded LDS row stride (shorts): 272B -> 2-way conflicts only

typedef __attribute__((ext_vector_type(8))) short short8;   // 8 bf16 (4 VGPRs)
typedef __attribute__((ext_vector_type(4))) float f32x4;

__device__ __forceinline__ unsigned short f2bf(float f) {
    unsigned u = __builtin_bit_cast(unsigned, f);
    u = (u + 0x7fffu + ((u >> 16) & 1u)) >> 16;   // RNE
    return (unsigned short)u;
}
__device__ __forceinline__ float bfbits2f(unsigned u) {  // u = bf16 in low 16
    u <<= 16;
    return __builtin_bit_cast(float, u);
}

// ---------------- MFMA helpers ----------------
// Verified gfx950 fragment layouts (learn_hip m89/m120):
//   A frag: lane holds A[m=lane&15][k=(lane>>4)*8 + 0..7]  (16B contiguous)
//   B frag: lane holds W[n=lane&15][k=(lane>>4)*8 + 0..7]  (W row-major [N][K] = B^T)
//   C/D:    col=lane&15, row=(lane>>4)*4 + reg
// lda = row stride of A in elements (HF for global, LDP for padded LDS).

template <int K, int NC>
__device__ __forceinline__
void mfma_cols(int row_tile, int col0,
               const unsigned short* __restrict__ A, int lda,
               const unsigned short* __restrict__ W, f32x4* acc) {
    int lane = threadIdx.x & 63;
    int m = lane & 15, quad = lane >> 4;
    const unsigned short* arow = A + (size_t)(row_tile * 16 + m) * lda + quad * 8;
    const short8* bp[NC];
#pragma unroll
    for (int c = 0; c < NC; ++c)
        bp[c] = (const short8*)(W + (size_t)(col0 + c * 16 + m) * K + quad * 8);
#pragma unroll
    for (int k0 = 0; k0 < K; k0 += 32) {
        short8 a = *(const short8*)(arow + k0);
#pragma unroll
        for (int c = 0; c < NC; ++c)
            acc[c] = __builtin_amdgcn_mfma_f32_16x16x32_bf16(a, bp[c][k0 >> 3], acc[c], 0, 0, 0);
    }
}

// epilogue; optionally adds tmp[row][col] (f32 partial) before act/store
template <int NC, bool OUT_BF16, bool RELU_OUT, bool HAS_BIAS, bool HAS_TMP>
__device__ __forceinline__
void epilogue_n(int row_tile, int col0, int N, const float* __restrict__ bias,
                const float* __restrict__ tmp, f32x4* acc, void* __restrict__ out) {
    int lane = threadIdx.x & 63;
    int m = lane & 15, quad = lane >> 4;
#pragma unroll
    for (int c = 0; c < NC; ++c) {
        int colg = col0 + c * 16 + m;
        float bv = HAS_BIAS ? bias[colg] : 0.f;
#pragma unroll
        for (int r = 0; r < 4; ++r) {
            int rowg = row_tile * 16 + quad * 4 + r;
            float v = acc[c][r] + bv;
            if (HAS_TMP) v += tmp[(size_t)rowg * N + colg];
            if (RELU_OUT) v = fmaxf(v, 0.f);
            if (OUT_BF16) ((unsigned short*)out)[(size_t)rowg * N + colg] = f2bf(v);
            else          ((float*)out)[(size_t)rowg * N + colg] = v;
        }
    }
}

__device__ __forceinline__ short8 pack8(float4 a, float4 b) {
    short8 r;
    r[0] = (short)f2bf(a.x); r[1] = (short)f2bf(a.y);
    r[2] = (short)f2bf(a.z); r[3] = (short)f2bf(a.w);
    r[4] = (short)f2bf(b.x); r[5] = (short)f2bf(b.y);
    r[6] = (short)f2bf(b.z); r[7] = (short)f2bf(b.w);
    return r;
}

// input projection: h0 = relu(x @ W_lin.T + b_lin); x, W_lin f32 (cvt in-loop —
// hides under the latency-bound fill anyway)
__device__ __forceinline__
void gemm1_wave(int row_tile, int col0, const float* __restrict__ x,
                const float* __restrict__ Wlin, const float* __restrict__ blin,
                unsigned short* __restrict__ h0) {
    int lane = threadIdx.x & 63;
    int m = lane & 15, quad = lane >> 4;
    const float* ar = x    + (size_t)(row_tile * 16 + m) * INF_ + quad * 8;
    const float* w0 = Wlin + (size_t)(col0 +  0 + m) * INF_ + quad * 8;
    const float* w1 = Wlin + (size_t)(col0 + 16 + m) * INF_ + quad * 8;
    const float* w2 = Wlin + (size_t)(col0 + 32 + m) * INF_ + quad * 8;
    const float* w3 = Wlin + (size_t)(col0 + 48 + m) * INF_ + quad * 8;
    f32x4 acc[4] = {};
#pragma unroll
    for (int k0 = 0; k0 < INF_; k0 += 32) {
        short8 a  = pack8(*(const float4*)(ar + k0), *(const float4*)(ar + k0 + 4));
        short8 b0 = pack8(*(const float4*)(w0 + k0), *(const float4*)(w0 + k0 + 4));
        short8 b1 = pack8(*(const float4*)(w1 + k0), *(const float4*)(w1 + k0 + 4));
        short8 b2 = pack8(*(const float4*)(w2 + k0), *(const float4*)(w2 + k0 + 4));
        short8 b3 = pack8(*(const float4*)(w3 + k0), *(const float4*)(w3 + k0 + 4));
        acc[0] = __builtin_amdgcn_mfma_f32_16x16x32_bf16(a, b0, acc[0], 0, 0, 0);
        acc[1] = __builtin_amdgcn_mfma_f32_16x16x32_bf16(a, b1, acc[1], 0, 0, 0);
        acc[2] = __builtin_amdgcn_mfma_f32_16x16x32_bf16(a, b2, acc[2], 0, 0, 0);
        acc[3] = __builtin_amdgcn_mfma_f32_16x16x32_bf16(a, b3, acc[3], 0, 0, 0);
    }
    epilogue_n<4, true, true, true, false>(row_tile, col0, HF, blin, nullptr, acc, h0);
}

// ---------------- fused: gemm1 || bucket fill || weight cvt ----------------
#define GB 313    // gemm1 blocks (2 row-tiles each, covers 625)
#define FB 2500   // fill blocks: 1 edge/thread (R6 lesson: waves > per-thread ILP)
#define CB 288    // weight-convert blocks (73728/256)

__global__ __launch_bounds__(256)
void fused_k(const float* __restrict__ x, const float* __restrict__ Wlin,
             const float* __restrict__ blin, unsigned short* __restrict__ h0,
             const int* __restrict__ src, const int* __restrict__ dst,
             int* __restrict__ cnt, unsigned short* __restrict__ colb, int E,
             const float* __restrict__ Wl1, const float* __restrict__ Wr1,
             const float* __restrict__ Wl2, const float* __restrict__ Wr2,
             const float* __restrict__ Wcls, unsigned short* __restrict__ wb) {
    int b = blockIdx.x;
    if (b < GB) {
        int wave = threadIdx.x >> 6;
        int row_tile = b * 2 + (wave >> 1);
        if (row_tile >= RT) return;
        gemm1_wave(row_tile, (wave & 1) * 64, x, Wlin, blin, h0);
    } else if (b < GB + FB) {
        int i = (b - GB) * 256 + threadIdx.x;
        if (i < E) {
            int d = dst[i];
            int pos = atomicAdd(&cnt[d], 1);
            if (pos < CAP) colb[(size_t)d * CAP + pos] = (unsigned short)src[i];
        }
    } else {
        int i = (b - GB - FB) * 256 + threadIdx.x;
        const float* s; int off;
        if      (i < 16384) { s = Wl1;  off = 0; }
        else if (i < 32768) { s = Wr1;  off = 16384; }
        else if (i < 49152) { s = Wl2;  off = 32768; }
        else if (i < 65536) { s = Wr2;  off = 49152; }
        else if (i < 73728) { s = Wcls; off = 65536; }
        else return;
        wb[i] = f2bf(s[i - off]);
    }
}

// ---------------- per-wave mean gather into an LDS row ----------------
// quad layout: 16 lanes x uint4 (16B) cover a 256B bf16 row; 4 lane-groups
// process edges j%4==q -> 4 rows in flight per load. __shfl all-lanes-active
// (ds_bpermute respects EXEC, R2 bug); loop break is wave-uniform.
__device__ __forceinline__
void gather_mean(const unsigned short* __restrict__ h, int deg,
                 const unsigned short* __restrict__ mycol,
                 unsigned short* __restrict__ msrow) {
    int lane = threadIdx.x & 63;
    int q   = lane >> 4;
    int r16 = lane & 15;
    int c = deg > CAP ? CAP : deg;
    const uint4* __restrict__ hp = (const uint4*)h;   // bf16 row = 16 uint4

    float a0 = 0.f, a1 = 0.f, a2 = 0.f, a3 = 0.f;
    float a4 = 0.f, a5 = 0.f, a6 = 0.f, a7 = 0.f;
    for (int base = 0; base < c; base += 64) {
        int mm = min(64, c - base);           // wave-uniform
        int colv = (base + lane < c) ? (int)mycol[base + lane] : 0;
#pragma unroll 4
        for (int jj = 0; jj < 16; ++jj) {
            if (jj * 4 >= mm) break;          // uniform break
            int e = jj * 4 + q;
            int s = __shfl(colv, e);          // all lanes active
            if (e < mm) {
                uint4 v = hp[(size_t)s * 16 + r16];
                a0 += bfbits2f(v.x & 0xffffu); a1 += bfbits2f(v.x >> 16);
                a2 += bfbits2f(v.y & 0xffffu); a3 += bfbits2f(v.y >> 16);
                a4 += bfbits2f(v.z & 0xffffu); a5 += bfbits2f(v.z >> 16);
                a6 += bfbits2f(v.w & 0xffffu); a7 += bfbits2f(v.w >> 16);
            }
        }
    }
    // reduce across the 4 lane-groups (bits 4,5) — all lanes active
    a0 += __shfl_xor(a0, 16); a0 += __shfl_xor(a0, 32);
    a1 += __shfl_xor(a1, 16); a1 += __shfl_xor(a1, 32);
    a2 += __shfl_xor(a2, 16); a2 += __shfl_xor(a2, 32);
    a3 += __shfl_xor(a3, 16); a3 += __shfl_xor(a3, 32);
    a4 += __shfl_xor(a4, 16); a4 += __shfl_xor(a4, 32);
    a5 += __shfl_xor(a5, 16); a5 += __shfl_xor(a5, 32);
    a6 += __shfl_xor(a6, 16); a6 += __shfl_xor(a6, 32);
    a7 += __shfl_xor(a7, 16); a7 += __shfl_xor(a7, 32);
    if (q == 0) {
        float inv = (deg > 0) ? 1.0f / (float)deg : 0.f;
        uint4 o;
        o.x = (unsigned)f2bf(a0 * inv) | ((unsigned)f2bf(a1 * inv) << 16);
        o.y = (unsigned)f2bf(a2 * inv) | ((unsigned)f2bf(a3 * inv) << 16);
        o.z = (unsigned)f2bf(a4 * inv) | ((unsigned)f2bf(a5 * inv) << 16);
        o.w = (unsigned)f2bf(a6 * inv) | ((unsigned)f2bf(a7 * inv) << 16);
        ((uint4*)msrow)[r16] = o;
    }
}

// ---------------- aggfin1: agg + full sage1 GEMM in one block ----------------
// 1024 threads = 16 waves = 16 nodes = one MFMA row-tile (block b <-> tile b).
// All waves gather their node's mean -> LDS. Waves 0-7 pre-compute h0@Wr1
// (global reads, overlaps straggler gathers), then after the barrier add
// means@Wl1 (LDS A-operand) + bias and write h1. No mv/tmp round-trips.
__global__ __launch_bounds__(1024)
void aggfin1_k(const unsigned short* __restrict__ h0, const int* __restrict__ cnt,
               const unsigned short* __restrict__ colb,
               const unsigned short* __restrict__ Wr, const unsigned short* __restrict__ Wl,
               const float* __restrict__ bias, unsigned short* __restrict__ h1) {
    __shared__ __align__(16) unsigned short ms[16][LDP];
    int wave = threadIdx.x >> 6;
    int node = blockIdx.x * 16 + wave;        // NN = 625*16 exactly
    gather_mean(h0, cnt[node], colb + (size_t)node * CAP, &ms[wave][0]);

    f32x4 acc[1] = {};
    if (wave < 8)
        mfma_cols<HF, 1>(blockIdx.x, wave * 16, h0, HF, Wr, acc);  // h0 @ Wr1
    __syncthreads();
    if (wave < 8) {
        mfma_cols<HF, 1>(0, wave * 16, &ms[0][0], LDP, Wl, acc);   // + means @ Wl1
        epilogue_n<1, true, false, true, false>(blockIdx.x, wave * 16, HF,
                                                bias, nullptr, acc, h1);
    }
}

// ---------------- aggfin2cls: agg + sage2 GEMM + relu + classifier ----------------
// Same structure; h2 row-tile lives only in LDS (padded), classifier runs from it.
__global__ __launch_bounds__(1024)
void aggfin2cls_k(const unsigned short* __restrict__ h1, const int* __restrict__ cnt,
                  const unsigned short* __restrict__ colb,
                  const unsigned short* __restrict__ Wr, const unsigned short* __restrict__ Wl,
                  const float* __restrict__ bias, const unsigned short* __restrict__ Wc,
                  float* __restrict__ out) {
    __shared__ __align__(16) unsigned short ms[16][LDP];
    __shared__ __align__(16) unsigned short h2s[16][LDP];
    int wave = threadIdx.x >> 6;
    int lane = threadIdx.x & 63;
    int m = lane & 15, quad = lane >> 4;
    int node = blockIdx.x * 16 + wave;
    gather_mean(h1, cnt[node], colb + (size_t)node * CAP, &ms[wave][0]);

    f32x4 acc[1] = {};
    if (wave < 8)
        mfma_cols<HF, 1>(blockIdx.x, wave * 16, h1, HF, Wr, acc);  // h1 @ Wr2
    __syncthreads();
    if (wave < 8) {
        mfma_cols<HF, 1>(0, wave * 16, &ms[0][0], LDP, Wl, acc);   // + means @ Wl2
        int colg = wave * 16 + m;
        float bv = bias[colg];
#pragma unroll
        for (int r = 0; r < 4; ++r) {
            float v = acc[0][r] + bv;
            h2s[quad * 4 + r][colg] = f2bf(fmaxf(v, 0.f));         // relu -> LDS
        }
    }
    __syncthreads();
    if (wave < 4) {
        f32x4 cacc[1] = {};
        mfma_cols<HF, 1>(0, wave * 16, &h2s[0][0], LDP, Wc, cacc); // h2 @ W_cls
        epilogue_n<1, false, false, false, false>(blockIdx.x, wave * 16, CLS,
                                                  nullptr, nullptr, cacc, out);
    }
}

// ---------------- launch ----------------

extern "C" void kernel_launch(void* const* d_in, const int* in_sizes, int n_in,
                              void* d_out, int out_size, void* d_ws, size_t ws_size,
                              hipStream_t stream) {
    const float* x      = (const float*)d_in[0];
    const int*   ei     = (const int*)d_in[1];
    const float* W_lin  = (const float*)d_in[2];
    const float* b_lin  = (const float*)d_in[3];
    const float* Wl1    = (const float*)d_in[4];
    const float* bl1    = (const float*)d_in[5];
    const float* Wr1    = (const float*)d_in[6];
    const float* Wl2    = (const float*)d_in[7];
    const float* bl2    = (const float*)d_in[8];
    const float* Wr2    = (const float*)d_in[9];
    const float* W_cls  = (const float*)d_in[10];
    float* out = (float*)d_out;

    const int E = in_sizes[1] / 2;
    const int* src = ei;
    const int* dst = ei + E;

    // workspace layout (bf16 stored as ushort)
    unsigned short* wb  = (unsigned short*)d_ws;          // 73728 weights bf16
    unsigned short* wbl1 = wb;
    unsigned short* wbr1 = wb + 16384;
    unsigned short* wbl2 = wb + 32768;
    unsigned short* wbr2 = wb + 49152;
    unsigned short* wbc  = wb + 65536;
    unsigned short* h0  = wb + 73728;                     // NN*HF
    unsigned short* h1  = h0 + (size_t)NN * HF;           // NN*HF
    int* cnt = (int*)(h1 + (size_t)NN * HF);              // NN
    unsigned short* colb = (unsigned short*)(cnt + NN);   // NN*CAP

    hipMemsetAsync(cnt, 0, NN * sizeof(int), stream);

    // ---- fused: input projection + relu || bucket fill || weight cvt ----
    fused_k<<<GB + FB + CB, 256, 0, stream>>>(
        x, W_lin, b_lin, h0, src, dst, cnt, colb, E,
        Wl1, Wr1, Wl2, Wr2, W_cls, wb);

    // ---- sage1 (agg + GEMM fused) ----
    aggfin1_k<<<RT, 1024, 0, stream>>>(h0, cnt, colb, wbr1, wbl1, bl1, h1);

    // ---- sage2 + relu + classifier (agg + GEMMs fused) ----
    aggfin2cls_k<<<RT, 1024, 0, stream>>>(h1, cnt, colb, wbr2, wbl2, bl2, wbc, out);
}